// Round 3
// baseline (441.741 us; speedup 1.0000x reference)
//
#include <hip/hip_runtime.h>
#include <hip/hip_bf16.h>

// ---------------------------------------------------------------------------
// Mlp_FMoE: fc1(MoE 2-expert top-1) -> DWConv3x3 -> GELU(exact) -> fc2(MoE)
// B=16 N=1024 C=512 Dh=2048 H=W=32, fp32 in/out.
// R3: counted-vmcnt pipelined GEMMs (T3/T4): raw s_barrier + vmcnt(N!=0),
//     double-buffered LDS, all operands via global_load_lds with XOR-swizzled
//     sources; x pre-split into bf16 hi/lo planes (k_prepx).
// ---------------------------------------------------------------------------

#define TOKS  16384
#define CIN   512
#define DHID  2048

typedef __attribute__((ext_vector_type(8))) __bf16 bf16x8;
typedef __attribute__((ext_vector_type(4))) float  f32x4;
typedef __attribute__((ext_vector_type(4))) float  float4v;
typedef __attribute__((ext_vector_type(4))) unsigned short ushort4v;

__device__ __forceinline__ unsigned short f2bf(float f) {
  union { float f; unsigned int u; } a; a.f = f;
  unsigned int u = a.u;
  unsigned int r = u + 0x7FFFu + ((u >> 16) & 1u);   // RNE
  return (unsigned short)(r >> 16);
}
__device__ __forceinline__ float bf2f(unsigned short h) {
  union { unsigned int u; float f; } a; a.u = ((unsigned int)h) << 16;
  return a.f;
}

// shift_quant: sign(w)*2^clip(round(log2(|w|+1e-12)),-14,0).
// round(log2(aw)) == e + (mantissa > sqrt(2)); exact via mantissa bit test.
__device__ __forceinline__ float squant(float w) {
  if (w == 0.0f) return 0.0f;
  float aw = fabsf(w) + 1e-12f;                 // fp32 add, as reference
  union { float f; unsigned u; } a; a.f = aw;
  int e = (int)((a.u >> 23) & 0xFFu) - 127;
  unsigned frac = a.u & 0x7FFFFFu;
  int shift = e + (frac >= 0x3504F4u ? 1 : 0);  // frac of sqrt(2)
  shift = min(max(shift, -14), 0);
  union { unsigned u; float f; } q; q.u = (unsigned)(shift + 127) << 23;
  return (w > 0.0f) ? q.f : -q.f;
}

#define GLDS16(gp, lp) __builtin_amdgcn_global_load_lds(                      \
    (const __attribute__((address_space(1))) void*)(gp),                      \
    (__attribute__((address_space(3))) void*)(lp), 16, 0, 0)

// ------------------------- weight prep -------------------------------------
__global__ void k_prep(const float* __restrict__ w0, const float* __restrict__ w1,
                       const float* __restrict__ w20, const float* __restrict__ w21,
                       unsigned short* __restrict__ w0hi, unsigned short* __restrict__ w0lo,
                       unsigned short* __restrict__ w1q, unsigned short* __restrict__ w20b,
                       unsigned short* __restrict__ w21b) {
  int i = blockIdx.x * 256 + threadIdx.x;
  if (i >= DHID * CIN) return;
  float v = w0[i];
  unsigned short h = f2bf(v);
  w0hi[i] = h;
  w0lo[i] = f2bf(v - bf2f(h));
  w1q[i]  = f2bf(squant(w1[i]));    // exact power of two -> exact in bf16
  w20b[i] = f2bf(w20[i]);
  w21b[i] = f2bf(squant(w21[i]));
}

// ------------------------- x split hi/lo ------------------------------------
__global__ void k_prepx(const float* __restrict__ x,
                        unsigned short* __restrict__ xhi, unsigned short* __restrict__ xlo) {
  int i = blockIdx.x * 256 + threadIdx.x;   // x4 floats
  float4v v = ((const float4v*)x)[i];
  ushort4v hv, lv;
  #pragma unroll
  for (int q = 0; q < 4; ++q) {
    unsigned short h = f2bf(v[q]);
    hv[q] = h;
    lv[q] = f2bf(v[q] - bf2f(h));
  }
  ((ushort4v*)xhi)[i] = hv;
  ((ushort4v*)xlo)[i] = lv;
}

// ------------------------- gate 1 (fp32 exact) ------------------------------
__global__ void k_gate1(const float* __restrict__ x, const float* __restrict__ wg1,
                        unsigned char* __restrict__ pick1) {
  int tok = blockIdx.x * 4 + (threadIdx.x >> 6);
  int l = threadIdx.x & 63;
  const float* xr = x + (size_t)tok * CIN;
  float s0 = 0.f, s1 = 0.f;
  for (int i = l; i < CIN; i += 64) {
    float v = xr[i];
    s0 += v * wg1[i * 2 + 0];
    s1 += v * wg1[i * 2 + 1];
  }
  for (int m = 32; m; m >>= 1) { s0 += __shfl_xor(s0, m); s1 += __shfl_xor(s1, m); }
  if (l == 0) pick1[tok] = (s0 >= s1) ? 0 : 1;   // argmax==0 on tie
}

// --------------- stable partition: perm = [expert0 toks..., expert1 toks...]
__global__ void k_scan(const unsigned char* __restrict__ pick, int* __restrict__ perm,
                       int* __restrict__ n0buf) {
  __shared__ int cnt[1024];
  const int t = threadIdx.x;
  unsigned char loc[16];
  int c0 = 0;
  #pragma unroll
  for (int i = 0; i < 16; ++i) { loc[i] = pick[t * 16 + i]; c0 += (loc[i] == 0); }
  cnt[t] = c0;
  __syncthreads();
  for (int off = 1; off < 1024; off <<= 1) {
    int v = cnt[t] + ((t >= off) ? cnt[t - off] : 0);
    __syncthreads();
    cnt[t] = v;
    __syncthreads();
  }
  int total0 = cnt[1023];
  int pre0 = cnt[t] - c0;
  int pre1 = t * 16 - pre0;
  if (t == 0) n0buf[0] = total0;
  int p0 = pre0, p1 = total0 + pre1;
  #pragma unroll
  for (int i = 0; i < 16; ++i) {
    int tok = t * 16 + i;
    if (loc[i] == 0) perm[p0++] = tok; else perm[p1++] = tok;
  }
}

// ------------------------- fc1: pipelined split-bf16 MoE GEMM ---------------
// 128x128 tile, BK=32, 4 waves. All 5 operand planes DMA'd via global_load_lds
// into double-buffered LDS; counted vmcnt keeps next tile's DMA in flight
// across barriers. XOR swizzle (16B granule ^ (row>>1)&3) on all tiles.
// LDS (ushort units):
//   A: db*8192 + h*4096 + row*32 + col          h in {hi,lo}
//   B: 16384 + db*12288 + e*4096 + row*32 + col e in {w0hi,w0lo,w1q}
__launch_bounds__(256, 2)
__global__ void k_fc1(const unsigned short* __restrict__ xhi,
                      const unsigned short* __restrict__ xlo,
                      const unsigned short* __restrict__ w0hi,
                      const unsigned short* __restrict__ w0lo,
                      const unsigned short* __restrict__ w1q,
                      const float* __restrict__ b0, const float* __restrict__ b1,
                      const int* __restrict__ perm, const int* __restrict__ n0buf,
                      float* __restrict__ h32) {
  __shared__ unsigned short sm[40960];   // 80 KiB
  const int t = threadIdx.x, wv = t >> 6, ln = t & 63;
  const int lr = ln & 15, lg = ln >> 4;
  const int tok0 = blockIdx.x * 128, nbase = blockIdx.y * 128;
  const int wm = (wv >> 1) * 64, wn = (wv & 1) * 64;
  const int n0 = n0buf[0];
  const bool do0 = (tok0 < n0), do1 = (tok0 + 128 > n0);

  int par[2];   // per-lane gathered A source rows for this wave's two rowblocks
  #pragma unroll
  for (int s = 0; s < 2; ++s)
    par[s] = perm[tok0 + ((s * 4 + wv) << 4) + (ln >> 2)];

  const int swsrc = (((ln & 3) ^ ((ln >> 3) & 3)) << 3);  // source-side granule
  const int swrd  = ((lg ^ ((lr >> 1) & 3)) << 3);        // read-side granule

  f32x4 acc0[4][4], acc1[4][4];
  #pragma unroll
  for (int i = 0; i < 4; ++i)
    #pragma unroll
    for (int j = 0; j < 4; ++j) {
      acc0[i][j] = f32x4{0.f, 0.f, 0.f, 0.f};
      acc1[i][j] = f32x4{0.f, 0.f, 0.f, 0.f};
    }

  auto STAGE = [&](int kt, int db) {   // 10 GLDS per wave
    const int k0 = kt * 32;
    #pragma unroll
    for (int s = 0; s < 2; ++s) {
      const int rowblk = s * 4 + wv;
      const int aoff = db * 8192 + (rowblk << 9);
      const int boff = 16384 + db * 12288 + (rowblk << 9);
      size_t ga = (size_t)par[s] * CIN + k0 + swsrc;
      size_t gb = (size_t)(nbase + (rowblk << 4) + (ln >> 2)) * CIN + k0 + swsrc;
      GLDS16(xhi + ga, &sm[aoff]);
      GLDS16(xlo + ga, &sm[aoff + 4096]);
      GLDS16(w0hi + gb, &sm[boff]);
      GLDS16(w0lo + gb, &sm[boff + 4096]);
      GLDS16(w1q + gb, &sm[boff + 8192]);
    }
  };

  auto COMPUTE = [&](int db) {
    bf16x8 ah[4], al[4];
    #pragma unroll
    for (int mt = 0; mt < 4; ++mt) {
      int ro = (wm + (mt << 4) + lr) * 32 + swrd;
      ah[mt] = *(const bf16x8*)&sm[db * 8192 + ro];
      al[mt] = *(const bf16x8*)&sm[db * 8192 + 4096 + ro];
    }
    __builtin_amdgcn_s_setprio(1);
    #pragma unroll
    for (int nt = 0; nt < 4; ++nt) {
      int bb = 16384 + db * 12288 + (wn + (nt << 4) + lr) * 32 + swrd;
      if (do0) {
        bf16x8 bh = *(const bf16x8*)&sm[bb];
        bf16x8 bl = *(const bf16x8*)&sm[bb + 4096];
        #pragma unroll
        for (int mt = 0; mt < 4; ++mt) {
          acc0[mt][nt] = __builtin_amdgcn_mfma_f32_16x16x32_bf16(ah[mt], bh, acc0[mt][nt], 0, 0, 0);
          acc0[mt][nt] = __builtin_amdgcn_mfma_f32_16x16x32_bf16(al[mt], bh, acc0[mt][nt], 0, 0, 0);
          acc0[mt][nt] = __builtin_amdgcn_mfma_f32_16x16x32_bf16(ah[mt], bl, acc0[mt][nt], 0, 0, 0);
        }
      }
      if (do1) {
        bf16x8 bq = *(const bf16x8*)&sm[bb + 8192];
        #pragma unroll
        for (int mt = 0; mt < 4; ++mt) {
          acc1[mt][nt] = __builtin_amdgcn_mfma_f32_16x16x32_bf16(ah[mt], bq, acc1[mt][nt], 0, 0, 0);
          acc1[mt][nt] = __builtin_amdgcn_mfma_f32_16x16x32_bf16(al[mt], bq, acc1[mt][nt], 0, 0, 0);
        }
      }
    }
    __builtin_amdgcn_s_setprio(0);
  };

  STAGE(0, 0);
  #pragma unroll 2
  for (int kt = 0; kt < 15; ++kt) {
    __builtin_amdgcn_s_barrier();               // prev compute's reads done
    __builtin_amdgcn_sched_barrier(0);
    STAGE(kt + 1, (kt + 1) & 1);
    asm volatile("s_waitcnt vmcnt(10)" ::: "memory");  // tile kt arrived
    __builtin_amdgcn_s_barrier();
    __builtin_amdgcn_sched_barrier(0);
    COMPUTE(kt & 1);
  }
  asm volatile("s_waitcnt vmcnt(0)" ::: "memory");
  __builtin_amdgcn_s_barrier();
  __builtin_amdgcn_sched_barrier(0);
  COMPUTE(1);

  // epilogue: expert by partition position, scatter through perm
  #pragma unroll
  for (int nt = 0; nt < 4; ++nt) {
    int d = nbase + wn + (nt << 4) + lr;
    float bi0 = b0[d], bi1 = b1[d];
    #pragma unroll
    for (int mt = 0; mt < 4; ++mt) {
      f32x4 v0 = acc0[mt][nt], v1 = acc1[mt][nt];
      #pragma unroll
      for (int rr = 0; rr < 4; ++rr) {
        int pos = tok0 + wm + (mt << 4) + (lg << 2) + rr;
        int tok = perm[pos];
        float val = (pos >= n0) ? (v1[rr] + bi1) : (v0[rr] + bi0);
        h32[(size_t)tok * DHID + d] = val;
      }
    }
  }
}

// ---------------- DWConv3x3 + bias + exact GELU + gate2 partials ------------
__global__ void k_conv(const float* __restrict__ h32, const float* __restrict__ dww,
                       const float* __restrict__ dwb, const float* __restrict__ wg2,
                       unsigned short* __restrict__ hb, float* __restrict__ part) {
  __shared__ float tile[10][32][32];
  const int dc = blockIdx.x;   // 0..63
  const int ys = blockIdx.y;   // 0..3
  const int b  = blockIdx.z;   // 0..15
  const int t = threadIdx.x;
  const int d0 = dc * 32, y0 = ys * 8;

  for (int p = 0; p < 10240; p += 256) {
    int idx = p + t;
    int dl = idx & 31, xx = (idx >> 5) & 31, ry = idx >> 10;
    int y = y0 - 1 + ry;
    float v = 0.f;
    if (y >= 0 && y < 32)
      v = h32[(size_t)(b * 1024 + y * 32 + xx) * DHID + d0 + dl];
    tile[ry][xx][dl] = v;
  }
  __syncthreads();

  const int dl = t & 31, xg = t >> 5;
  const int d = d0 + dl;
  float kk[9];
  #pragma unroll
  for (int i = 0; i < 9; ++i) kk[i] = dww[d * 9 + i];
  const float bias = dwb[d];
  const float g0 = wg2[d * 2 + 0], g1 = wg2[d * 2 + 1];

  for (int yy = 0; yy < 8; ++yy) {
    int ry = yy + 1;
    #pragma unroll
    for (int xi = 0; xi < 4; ++xi) {
      int xx = xg * 4 + xi;
      float s = bias;
      #pragma unroll
      for (int dy = -1; dy <= 1; ++dy)
        #pragma unroll
        for (int dx = -1; dx <= 1; ++dx) {
          int xs = xx + dx;
          float v = (xs >= 0 && xs < 32) ? tile[ry + dy][xs][dl] : 0.f;
          s += v * kk[(dy + 1) * 3 + (dx + 1)];
        }
      float gg = 0.5f * s * (1.0f + erff(s * 0.70710678118654752f));  // exact gelu
      int tok = b * 1024 + (y0 + yy) * 32 + xx;
      hb[(size_t)tok * DHID + d] = f2bf(gg);
      float p0 = gg * g0, p1 = gg * g1;
      for (int m = 16; m; m >>= 1) { p0 += __shfl_xor(p0, m); p1 += __shfl_xor(p1, m); }
      if (dl == 0) {
        part[(size_t)tok * 128 + dc] = p0;
        part[(size_t)tok * 128 + 64 + dc] = p1;
      }
    }
  }
}

// ------------------------- gate 2 reduce (wave per token) -------------------
__global__ void k_gate2(const float* __restrict__ part, unsigned char* __restrict__ pick2) {
  int tok = blockIdx.x * 4 + (threadIdx.x >> 6);
  int l = threadIdx.x & 63;
  const float* pr = part + (size_t)tok * 128;
  float s0 = pr[l], s1 = pr[64 + l];
  for (int m = 32; m; m >>= 1) { s0 += __shfl_xor(s0, m); s1 += __shfl_xor(s1, m); }
  if (l == 0) pick2[tok] = (s0 >= s1) ? 0 : 1;
}

// ------------------------- fc2: pipelined bf16 MoE GEMM ---------------------
// LDS (ushort): A: db*4096 + row*32 + col ; B: 8192 + db*8192 + e*4096 + ...
__launch_bounds__(256, 2)
__global__ void k_fc2(const unsigned short* __restrict__ hb,
                      const unsigned short* __restrict__ w20b,
                      const unsigned short* __restrict__ w21b,
                      const float* __restrict__ b0, const float* __restrict__ b1,
                      const int* __restrict__ perm, const int* __restrict__ n0buf,
                      float* __restrict__ out) {
  __shared__ unsigned short sm[24576];   // 48 KiB
  const int t = threadIdx.x, wv = t >> 6, ln = t & 63;
  const int lr = ln & 15, lg = ln >> 4;
  const int tok0 = blockIdx.x * 128, nbase = blockIdx.y * 128;
  const int wm = (wv >> 1) * 64, wn = (wv & 1) * 64;
  const int n0 = n0buf[0];
  const bool do0 = (tok0 < n0), do1 = (tok0 + 128 > n0);

  int par[2];
  #pragma unroll
  for (int s = 0; s < 2; ++s)
    par[s] = perm[tok0 + ((s * 4 + wv) << 4) + (ln >> 2)];

  const int swsrc = (((ln & 3) ^ ((ln >> 3) & 3)) << 3);
  const int swrd  = ((lg ^ ((lr >> 1) & 3)) << 3);

  f32x4 acc0[4][4], acc1[4][4];
  #pragma unroll
  for (int i = 0; i < 4; ++i)
    #pragma unroll
    for (int j = 0; j < 4; ++j) {
      acc0[i][j] = f32x4{0.f, 0.f, 0.f, 0.f};
      acc1[i][j] = f32x4{0.f, 0.f, 0.f, 0.f};
    }

  auto STAGE = [&](int kt, int db) {   // 6 GLDS per wave
    const int k0 = kt * 32;
    #pragma unroll
    for (int s = 0; s < 2; ++s) {
      const int rowblk = s * 4 + wv;
      const int aoff = db * 4096 + (rowblk << 9);
      const int boff = 8192 + db * 8192 + (rowblk << 9);
      size_t ga = (size_t)par[s] * DHID + k0 + swsrc;
      size_t gb = (size_t)(nbase + (rowblk << 4) + (ln >> 2)) * DHID + k0 + swsrc;
      GLDS16(hb + ga, &sm[aoff]);
      GLDS16(w20b + gb, &sm[boff]);
      GLDS16(w21b + gb, &sm[boff + 4096]);
    }
  };

  auto COMPUTE = [&](int db) {
    bf16x8 a[4];
    #pragma unroll
    for (int mt = 0; mt < 4; ++mt)
      a[mt] = *(const bf16x8*)&sm[db * 4096 + (wm + (mt << 4) + lr) * 32 + swrd];
    __builtin_amdgcn_s_setprio(1);
    #pragma unroll
    for (int nt = 0; nt < 4; ++nt) {
      int bb = 8192 + db * 8192 + (wn + (nt << 4) + lr) * 32 + swrd;
      if (do0) {
        bf16x8 b0f = *(const bf16x8*)&sm[bb];
        #pragma unroll
        for (int mt = 0; mt < 4; ++mt)
          acc0[mt][nt] = __builtin_amdgcn_mfma_f32_16x16x32_bf16(a[mt], b0f, acc0[mt][nt], 0, 0, 0);
      }
      if (do1) {
        bf16x8 b1f = *(const bf16x8*)&sm[bb + 4096];
        #pragma unroll
        for (int mt = 0; mt < 4; ++mt)
          acc1[mt][nt] = __builtin_amdgcn_mfma_f32_16x16x32_bf16(a[mt], b1f, acc1[mt][nt], 0, 0, 0);
      }
    }
    __builtin_amdgcn_s_setprio(0);
  };

  STAGE(0, 0);
  #pragma unroll 2
  for (int kt = 0; kt < 63; ++kt) {
    __builtin_amdgcn_s_barrier();
    __builtin_amdgcn_sched_barrier(0);
    STAGE(kt + 1, (kt + 1) & 1);
    asm volatile("s_waitcnt vmcnt(6)" ::: "memory");
    __builtin_amdgcn_s_barrier();
    __builtin_amdgcn_sched_barrier(0);
    COMPUTE(kt & 1);
  }
  asm volatile("s_waitcnt vmcnt(0)" ::: "memory");
  __builtin_amdgcn_s_barrier();
  __builtin_amdgcn_sched_barrier(0);
  COMPUTE(1);

  #pragma unroll
  for (int nt = 0; nt < 4; ++nt) {
    int c = nbase + wn + (nt << 4) + lr;
    float bi0 = b0[c], bi1 = b1[c];
    #pragma unroll
    for (int mt = 0; mt < 4; ++mt) {
      f32x4 v0 = acc0[mt][nt], v1 = acc1[mt][nt];
      #pragma unroll
      for (int rr = 0; rr < 4; ++rr) {
        int pos = tok0 + wm + (mt << 4) + (lg << 2) + rr;
        int tok = perm[pos];
        float val = (pos >= n0) ? (v1[rr] + bi1) : (v0[rr] + bi0);
        out[(size_t)tok * CIN + c] = val;
      }
    }
  }
}

// ---------------------------------------------------------------------------
extern "C" void kernel_launch(void* const* d_in, const int* in_sizes, int n_in,
                              void* d_out, int out_size, void* d_ws, size_t ws_size,
                              hipStream_t stream) {
  (void)in_sizes; (void)n_in; (void)out_size; (void)ws_size;
  const float* x   = (const float*)d_in[0];
  const float* wg1 = (const float*)d_in[3];
  const float* w0  = (const float*)d_in[4];
  const float* b0  = (const float*)d_in[5];
  const float* w1  = (const float*)d_in[6];
  const float* b1  = (const float*)d_in[7];
  const float* dww = (const float*)d_in[8];
  const float* dwb = (const float*)d_in[9];
  const float* wg2 = (const float*)d_in[10];
  const float* w20 = (const float*)d_in[11];
  const float* b20 = (const float*)d_in[12];
  const float* w21 = (const float*)d_in[13];
  const float* b21 = (const float*)d_in[14];
  float* out = (float*)d_out;

  char* ws = (char*)d_ws;
  const size_t MB2 = 1u << 21;
  unsigned short* w0hi = (unsigned short*)(ws + 0 * MB2);
  unsigned short* w0lo = (unsigned short*)(ws + 1 * MB2);
  unsigned short* w1q  = (unsigned short*)(ws + 2 * MB2);
  unsigned short* w20b = (unsigned short*)(ws + 3 * MB2);
  unsigned short* w21b = (unsigned short*)(ws + 4 * MB2);
  char* p = ws + 5 * MB2;
  unsigned short* xhi = (unsigned short*)p;            p += (size_t)TOKS * CIN * 2;
  unsigned short* xlo = (unsigned short*)p;            p += (size_t)TOKS * CIN * 2;
  unsigned char* pick1 = (unsigned char*)p;            p += 65536;
  unsigned char* pick2 = (unsigned char*)p;            p += 65536;
  int* perm1 = (int*)p;                                p += TOKS * 4;
  int* perm2 = (int*)p;                                p += TOKS * 4;
  int* n0a   = (int*)p;                                p += 256;
  int* n0b   = (int*)p;                                p += 256;
  float* part = (float*)p;                             p += (size_t)TOKS * 128 * 4;
  float* h32  = (float*)p;                             p += (size_t)TOKS * DHID * 4;
  unsigned short* hb = (unsigned short*)p;             // +64 MiB; total ~245 MiB

  k_prep <<<4096, 256, 0, stream>>>(w0, w1, w20, w21, w0hi, w0lo, w1q, w20b, w21b);
  k_prepx<<<8192, 256, 0, stream>>>(x, xhi, xlo);
  k_gate1<<<4096, 256, 0, stream>>>(x, wg1, pick1);
  k_scan <<<1, 1024, 0, stream>>>(pick1, perm1, n0a);
  k_fc1  <<<dim3(128, 16), 256, 0, stream>>>(xhi, xlo, w0hi, w0lo, w1q, b0, b1, perm1, n0a, h32);
  k_conv <<<dim3(64, 4, 16), 256, 0, stream>>>(h32, dww, dwb, wg2, hb, part);
  k_gate2<<<4096, 256, 0, stream>>>(part, pick2);
  k_scan <<<1, 1024, 0, stream>>>(pick2, perm2, n0b);
  k_fc2  <<<dim3(128, 4), 256, 0, stream>>>(hb, w20b, w21b, b20, b21, perm2, n0b, out);
}

// Round 4
// 424.566 us; speedup vs baseline: 1.0405x; 1.0405x over previous
//
#include <hip/hip_runtime.h>
#include <hip/hip_bf16.h>

// ---------------------------------------------------------------------------
// Mlp_FMoE: fc1(MoE 2-expert top-1) -> DWConv3x3 -> GELU(exact) -> fc2(MoE)
// B=16 N=1024 C=512 Dh=2048 H=W=32, fp32 in/out.
// R4: vectorized conv (float4 LDS/global, 8-lane gate reduce); GEMM epilogues
//     via LDS transpose -> coalesced float4 row stores; XCD-grouped block
//     swizzle (A-panel L2 reuse); exact vmcnt counts (race fix).
// ---------------------------------------------------------------------------

#define TOKS  16384
#define CIN   512
#define DHID  2048

typedef __attribute__((ext_vector_type(8))) __bf16 bf16x8;
typedef __attribute__((ext_vector_type(4))) float  f32x4;
typedef __attribute__((ext_vector_type(4))) float  float4v;
typedef __attribute__((ext_vector_type(4))) unsigned short ushort4v;

__device__ __forceinline__ unsigned short f2bf(float f) {
  union { float f; unsigned int u; } a; a.f = f;
  unsigned int u = a.u;
  unsigned int r = u + 0x7FFFu + ((u >> 16) & 1u);   // RNE
  return (unsigned short)(r >> 16);
}
__device__ __forceinline__ float bf2f(unsigned short h) {
  union { unsigned int u; float f; } a; a.u = ((unsigned int)h) << 16;
  return a.f;
}

// shift_quant: sign(w)*2^clip(round(log2(|w|+1e-12)),-14,0).
// round(log2(aw)) == e + (mantissa > sqrt(2)); exact via mantissa bit test.
__device__ __forceinline__ float squant(float w) {
  if (w == 0.0f) return 0.0f;
  float aw = fabsf(w) + 1e-12f;                 // fp32 add, as reference
  union { float f; unsigned u; } a; a.f = aw;
  int e = (int)((a.u >> 23) & 0xFFu) - 127;
  unsigned frac = a.u & 0x7FFFFFu;
  int shift = e + (frac >= 0x3504F4u ? 1 : 0);  // frac of sqrt(2)
  shift = min(max(shift, -14), 0);
  union { unsigned u; float f; } q; q.u = (unsigned)(shift + 127) << 23;
  return (w > 0.0f) ? q.f : -q.f;
}

#define GLDS16(gp, lp) __builtin_amdgcn_global_load_lds(                      \
    (const __attribute__((address_space(1))) void*)(gp),                      \
    (__attribute__((address_space(3))) void*)(lp), 16, 0, 0)

// ------------------------- weight prep -------------------------------------
__global__ void k_prep(const float* __restrict__ w0, const float* __restrict__ w1,
                       const float* __restrict__ w20, const float* __restrict__ w21,
                       unsigned short* __restrict__ w0hi, unsigned short* __restrict__ w0lo,
                       unsigned short* __restrict__ w1q, unsigned short* __restrict__ w20b,
                       unsigned short* __restrict__ w21b) {
  int i = blockIdx.x * 256 + threadIdx.x;
  if (i >= DHID * CIN) return;
  float v = w0[i];
  unsigned short h = f2bf(v);
  w0hi[i] = h;
  w0lo[i] = f2bf(v - bf2f(h));
  w1q[i]  = f2bf(squant(w1[i]));    // exact power of two -> exact in bf16
  w20b[i] = f2bf(w20[i]);
  w21b[i] = f2bf(squant(w21[i]));
}

// ------------------------- x split hi/lo ------------------------------------
__global__ void k_prepx(const float* __restrict__ x,
                        unsigned short* __restrict__ xhi, unsigned short* __restrict__ xlo) {
  int i = blockIdx.x * 256 + threadIdx.x;   // x4 floats
  float4v v = ((const float4v*)x)[i];
  ushort4v hv, lv;
  #pragma unroll
  for (int q = 0; q < 4; ++q) {
    unsigned short h = f2bf(v[q]);
    hv[q] = h;
    lv[q] = f2bf(v[q] - bf2f(h));
  }
  ((ushort4v*)xhi)[i] = hv;
  ((ushort4v*)xlo)[i] = lv;
}

// ------------------------- gate 1 (fp32 exact) ------------------------------
__global__ void k_gate1(const float* __restrict__ x, const float* __restrict__ wg1,
                        unsigned char* __restrict__ pick1) {
  int tok = blockIdx.x * 4 + (threadIdx.x >> 6);
  int l = threadIdx.x & 63;
  const float* xr = x + (size_t)tok * CIN;
  float s0 = 0.f, s1 = 0.f;
  for (int i = l; i < CIN; i += 64) {
    float v = xr[i];
    s0 += v * wg1[i * 2 + 0];
    s1 += v * wg1[i * 2 + 1];
  }
  for (int m = 32; m; m >>= 1) { s0 += __shfl_xor(s0, m); s1 += __shfl_xor(s1, m); }
  if (l == 0) pick1[tok] = (s0 >= s1) ? 0 : 1;   // argmax==0 on tie
}

// --------------- stable partition: perm = [expert0 toks..., expert1 toks...]
__global__ void k_scan(const unsigned char* __restrict__ pick, int* __restrict__ perm,
                       int* __restrict__ n0buf) {
  __shared__ int cnt[1024];
  const int t = threadIdx.x;
  unsigned char loc[16];
  int c0 = 0;
  #pragma unroll
  for (int i = 0; i < 16; ++i) { loc[i] = pick[t * 16 + i]; c0 += (loc[i] == 0); }
  cnt[t] = c0;
  __syncthreads();
  for (int off = 1; off < 1024; off <<= 1) {
    int v = cnt[t] + ((t >= off) ? cnt[t - off] : 0);
    __syncthreads();
    cnt[t] = v;
    __syncthreads();
  }
  int total0 = cnt[1023];
  int pre0 = cnt[t] - c0;
  int pre1 = t * 16 - pre0;
  if (t == 0) n0buf[0] = total0;
  int p0 = pre0, p1 = total0 + pre1;
  #pragma unroll
  for (int i = 0; i < 16; ++i) {
    int tok = t * 16 + i;
    if (loc[i] == 0) perm[p0++] = tok; else perm[p1++] = tok;
  }
}

// ------------------------- fc1: pipelined split-bf16 MoE GEMM ---------------
// 128x128 tile, BK=32, 4 waves; counted-vmcnt double-buffered DMA staging.
// Block decode groups all 16 col-blocks of a token-block on one XCD.
__launch_bounds__(256, 2)
__global__ void k_fc1(const unsigned short* __restrict__ xhi,
                      const unsigned short* __restrict__ xlo,
                      const unsigned short* __restrict__ w0hi,
                      const unsigned short* __restrict__ w0lo,
                      const unsigned short* __restrict__ w1q,
                      const float* __restrict__ b0, const float* __restrict__ b1,
                      const int* __restrict__ perm, const int* __restrict__ n0buf,
                      float* __restrict__ h32) {
  __shared__ unsigned short sm[40960];   // 80 KiB
  const int t = threadIdx.x, wv = t >> 6, ln = t & 63;
  const int lr = ln & 15, lg = ln >> 4;
  // swizzle: same token-block's 16 col-blocks share an XCD (A L2 reuse)
  const int g = blockIdx.x, q = g >> 3;
  const int tok0 = ((g & 7) + ((q >> 4) << 3)) * 128;
  const int nbase = (q & 15) * 128;
  const int wm = (wv >> 1) * 64, wn = (wv & 1) * 64;
  const int n0 = n0buf[0];
  const bool do0 = (tok0 < n0), do1 = (tok0 + 128 > n0);

  int par[2];
  #pragma unroll
  for (int s = 0; s < 2; ++s)
    par[s] = perm[tok0 + ((s * 4 + wv) << 4) + (ln >> 2)];

  const int swsrc = (((ln & 3) ^ ((ln >> 3) & 3)) << 3);
  const int swrd  = ((lg ^ ((lr >> 1) & 3)) << 3);

  f32x4 acc0[4][4], acc1[4][4];
  #pragma unroll
  for (int i = 0; i < 4; ++i)
    #pragma unroll
    for (int j = 0; j < 4; ++j) {
      acc0[i][j] = f32x4{0.f, 0.f, 0.f, 0.f};
      acc1[i][j] = f32x4{0.f, 0.f, 0.f, 0.f};
    }

  auto STAGE = [&](int kt, int db) {   // exactly 10 GLDS per wave, always
    const int k0 = kt * 32;
    #pragma unroll
    for (int s = 0; s < 2; ++s) {
      const int rowblk = s * 4 + wv;
      const int aoff = db * 8192 + (rowblk << 9);
      const int boff = 16384 + db * 12288 + (rowblk << 9);
      size_t ga = (size_t)par[s] * CIN + k0 + swsrc;
      size_t gb = (size_t)(nbase + (rowblk << 4) + (ln >> 2)) * CIN + k0 + swsrc;
      GLDS16(xhi + ga, &sm[aoff]);
      GLDS16(xlo + ga, &sm[aoff + 4096]);
      GLDS16(w0hi + gb, &sm[boff]);
      GLDS16(w0lo + gb, &sm[boff + 4096]);
      GLDS16(w1q + gb, &sm[boff + 8192]);
    }
  };

  auto COMPUTE = [&](int db) {
    bf16x8 ah[4], al[4];
    #pragma unroll
    for (int mt = 0; mt < 4; ++mt) {
      int ro = (wm + (mt << 4) + lr) * 32 + swrd;
      ah[mt] = *(const bf16x8*)&sm[db * 8192 + ro];
      al[mt] = *(const bf16x8*)&sm[db * 8192 + 4096 + ro];
    }
    __builtin_amdgcn_s_setprio(1);
    #pragma unroll
    for (int nt = 0; nt < 4; ++nt) {
      int bb = 16384 + db * 12288 + (wn + (nt << 4) + lr) * 32 + swrd;
      if (do0) {
        bf16x8 bh = *(const bf16x8*)&sm[bb];
        bf16x8 bl = *(const bf16x8*)&sm[bb + 4096];
        #pragma unroll
        for (int mt = 0; mt < 4; ++mt) {
          acc0[mt][nt] = __builtin_amdgcn_mfma_f32_16x16x32_bf16(ah[mt], bh, acc0[mt][nt], 0, 0, 0);
          acc0[mt][nt] = __builtin_amdgcn_mfma_f32_16x16x32_bf16(al[mt], bh, acc0[mt][nt], 0, 0, 0);
          acc0[mt][nt] = __builtin_amdgcn_mfma_f32_16x16x32_bf16(ah[mt], bl, acc0[mt][nt], 0, 0, 0);
        }
      }
      if (do1) {
        bf16x8 bq = *(const bf16x8*)&sm[bb + 8192];
        #pragma unroll
        for (int mt = 0; mt < 4; ++mt) {
          acc1[mt][nt] = __builtin_amdgcn_mfma_f32_16x16x32_bf16(ah[mt], bq, acc1[mt][nt], 0, 0, 0);
          acc1[mt][nt] = __builtin_amdgcn_mfma_f32_16x16x32_bf16(al[mt], bq, acc1[mt][nt], 0, 0, 0);
        }
      }
    }
    __builtin_amdgcn_s_setprio(0);
  };

  STAGE(0, 0);
  #pragma unroll 2
  for (int kt = 0; kt < 15; ++kt) {
    __builtin_amdgcn_s_barrier();
    __builtin_amdgcn_sched_barrier(0);
    STAGE(kt + 1, (kt + 1) & 1);
    asm volatile("s_waitcnt vmcnt(10)" ::: "memory");  // tile kt fully arrived
    __builtin_amdgcn_s_barrier();
    __builtin_amdgcn_sched_barrier(0);
    COMPUTE(kt & 1);
  }
  asm volatile("s_waitcnt vmcnt(0)" ::: "memory");
  __builtin_amdgcn_s_barrier();
  __builtin_amdgcn_sched_barrier(0);
  COMPUTE(1);

  // epilogue: LDS transpose (stride 68 floats = 17x16B) -> float4 row stores
  __syncthreads();
  float* smf = (float*)sm;
  float bi0[4], bi1[4];
  #pragma unroll
  for (int nt = 0; nt < 4; ++nt) {
    int d = nbase + wn + (nt << 4) + lr;
    bi0[nt] = b0[d]; bi1[nt] = b1[d];
  }
  #pragma unroll
  for (int mt = 0; mt < 4; ++mt) {
    #pragma unroll
    for (int nt = 0; nt < 4; ++nt) {
      f32x4 v0 = acc0[mt][nt], v1 = acc1[mt][nt];
      #pragma unroll
      for (int rr = 0; rr < 4; ++rr) {
        int pos = tok0 + wm + (mt << 4) + (lg << 2) + rr;
        float val = (pos >= n0) ? (v1[rr] + bi1[nt]) : (v0[rr] + bi0[nt]);
        smf[wv * 1088 + ((lg << 2) + rr) * 68 + (nt << 4) + lr] = val;
      }
    }
    #pragma unroll
    for (int p = 0; p < 4; ++p) {
      int row = (p << 2) + (ln >> 4);   // 0..15 within this mt block
      f32x4 vv = *(const f32x4*)&smf[wv * 1088 + row * 68 + ((ln & 15) << 2)];
      int tok = perm[tok0 + wm + (mt << 4) + row];
      *(f32x4*)&h32[(size_t)tok * DHID + nbase + wn + ((ln & 15) << 2)] = vv;
    }
  }
}

// ---------------- DWConv3x3 + bias + exact GELU + gate2 partials ------------
// float4-vectorized: thread=(x 0..31, d4 0..7) over 4 d's; 8-lane gate reduce.
__launch_bounds__(256)
__global__ void k_conv(const float* __restrict__ h32, const float* __restrict__ dww,
                       const float* __restrict__ dwb, const float* __restrict__ wg2,
                       unsigned short* __restrict__ hb, float* __restrict__ part) {
  __shared__ float4v tile[10][32][8];   // 40 KiB
  const int dc = blockIdx.x;   // 0..63 (32-d chunk)
  const int ys = blockIdx.y;   // 0..3
  const int b  = blockIdx.z;   // 0..15
  const int t = threadIdx.x;
  const int d0 = dc * 32, y0 = ys * 8;
  const int dl4 = t & 7, xq = t >> 3;

  #pragma unroll
  for (int ry = 0; ry < 10; ++ry) {
    int y = y0 - 1 + ry;
    float4v v = {0.f, 0.f, 0.f, 0.f};
    if (y >= 0 && y < 32)
      v = *(const float4v*)&h32[(size_t)(b * 1024 + y * 32 + xq) * DHID + d0 + dl4 * 4];
    tile[ry][xq][dl4] = v;
  }
  __syncthreads();

  const int d = d0 + dl4 * 4;
  float4v kk[9];
  #pragma unroll
  for (int i = 0; i < 9; ++i) {
    kk[i][0] = dww[(d + 0) * 9 + i]; kk[i][1] = dww[(d + 1) * 9 + i];
    kk[i][2] = dww[(d + 2) * 9 + i]; kk[i][3] = dww[(d + 3) * 9 + i];
  }
  const float4v bias = *(const float4v*)&dwb[d];
  float4v g0v, g1v;
  #pragma unroll
  for (int j = 0; j < 4; ++j) { g0v[j] = wg2[(d + j) * 2]; g1v[j] = wg2[(d + j) * 2 + 1]; }

  #pragma unroll
  for (int yy = 0; yy < 8; ++yy) {
    float4v s = bias;
    #pragma unroll
    for (int dy = 0; dy < 3; ++dy)
      #pragma unroll
      for (int dx = 0; dx < 3; ++dx) {
        int xs = xq + dx - 1;
        if (xs >= 0 && xs < 32) {
          float4v v = tile[yy + dy][xs][dl4];
          float4v k = kk[dy * 3 + dx];
          s[0] += v[0] * k[0]; s[1] += v[1] * k[1];
          s[2] += v[2] * k[2]; s[3] += v[3] * k[3];
        }
      }
    float4v gg;
    #pragma unroll
    for (int j = 0; j < 4; ++j)
      gg[j] = 0.5f * s[j] * (1.0f + erff(s[j] * 0.70710678118654752f));  // exact
    int tok = b * 1024 + (y0 + yy) * 32 + xq;
    ushort4v hv;
    #pragma unroll
    for (int j = 0; j < 4; ++j) hv[j] = f2bf(gg[j]);
    *(ushort4v*)&hb[(size_t)tok * DHID + d] = hv;
    float p0 = gg[0] * g0v[0] + gg[1] * g0v[1] + gg[2] * g0v[2] + gg[3] * g0v[3];
    float p1 = gg[0] * g1v[0] + gg[1] * g1v[1] + gg[2] * g1v[2] + gg[3] * g1v[3];
    p0 += __shfl_xor(p0, 1); p0 += __shfl_xor(p0, 2); p0 += __shfl_xor(p0, 4);
    p1 += __shfl_xor(p1, 1); p1 += __shfl_xor(p1, 2); p1 += __shfl_xor(p1, 4);
    if (dl4 == 0) {
      part[(size_t)tok * 128 + dc] = p0;
      part[(size_t)tok * 128 + 64 + dc] = p1;
    }
  }
}

// ------------------------- gate 2 reduce (wave per token) -------------------
__global__ void k_gate2(const float* __restrict__ part, unsigned char* __restrict__ pick2) {
  int tok = blockIdx.x * 4 + (threadIdx.x >> 6);
  int l = threadIdx.x & 63;
  const float* pr = part + (size_t)tok * 128;
  float s0 = pr[l], s1 = pr[64 + l];
  for (int m = 32; m; m >>= 1) { s0 += __shfl_xor(s0, m); s1 += __shfl_xor(s1, m); }
  if (l == 0) pick2[tok] = (s0 >= s1) ? 0 : 1;
}

// ------------------------- fc2: pipelined bf16 MoE GEMM ---------------------
__launch_bounds__(256, 2)
__global__ void k_fc2(const unsigned short* __restrict__ hb,
                      const unsigned short* __restrict__ w20b,
                      const unsigned short* __restrict__ w21b,
                      const float* __restrict__ b0, const float* __restrict__ b1,
                      const int* __restrict__ perm, const int* __restrict__ n0buf,
                      float* __restrict__ out) {
  __shared__ unsigned short sm[24576];   // 48 KiB
  const int t = threadIdx.x, wv = t >> 6, ln = t & 63;
  const int lr = ln & 15, lg = ln >> 4;
  const int g = blockIdx.x, q = g >> 3;
  const int tok0 = ((g & 7) + ((q >> 2) << 3)) * 128;
  const int nbase = (q & 3) * 128;
  const int wm = (wv >> 1) * 64, wn = (wv & 1) * 64;
  const int n0 = n0buf[0];
  const bool do0 = (tok0 < n0), do1 = (tok0 + 128 > n0);

  int par[2];
  #pragma unroll
  for (int s = 0; s < 2; ++s)
    par[s] = perm[tok0 + ((s * 4 + wv) << 4) + (ln >> 2)];

  const int swsrc = (((ln & 3) ^ ((ln >> 3) & 3)) << 3);
  const int swrd  = ((lg ^ ((lr >> 1) & 3)) << 3);

  f32x4 acc0[4][4], acc1[4][4];
  #pragma unroll
  for (int i = 0; i < 4; ++i)
    #pragma unroll
    for (int j = 0; j < 4; ++j) {
      acc0[i][j] = f32x4{0.f, 0.f, 0.f, 0.f};
      acc1[i][j] = f32x4{0.f, 0.f, 0.f, 0.f};
    }

  auto STAGE = [&](int kt, int db) {   // exactly 6 GLDS per wave, always
    const int k0 = kt * 32;
    #pragma unroll
    for (int s = 0; s < 2; ++s) {
      const int rowblk = s * 4 + wv;
      const int aoff = db * 4096 + (rowblk << 9);
      const int boff = 8192 + db * 8192 + (rowblk << 9);
      size_t ga = (size_t)par[s] * DHID + k0 + swsrc;
      size_t gb = (size_t)(nbase + (rowblk << 4) + (ln >> 2)) * DHID + k0 + swsrc;
      GLDS16(hb + ga, &sm[aoff]);
      GLDS16(w20b + gb, &sm[boff]);
      GLDS16(w21b + gb, &sm[boff + 4096]);
    }
  };

  auto COMPUTE = [&](int db) {
    bf16x8 a[4];
    #pragma unroll
    for (int mt = 0; mt < 4; ++mt)
      a[mt] = *(const bf16x8*)&sm[db * 4096 + (wm + (mt << 4) + lr) * 32 + swrd];
    __builtin_amdgcn_s_setprio(1);
    #pragma unroll
    for (int nt = 0; nt < 4; ++nt) {
      int bb = 8192 + db * 8192 + (wn + (nt << 4) + lr) * 32 + swrd;
      if (do0) {
        bf16x8 b0f = *(const bf16x8*)&sm[bb];
        #pragma unroll
        for (int mt = 0; mt < 4; ++mt)
          acc0[mt][nt] = __builtin_amdgcn_mfma_f32_16x16x32_bf16(a[mt], b0f, acc0[mt][nt], 0, 0, 0);
      }
      if (do1) {
        bf16x8 b1f = *(const bf16x8*)&sm[bb + 4096];
        #pragma unroll
        for (int mt = 0; mt < 4; ++mt)
          acc1[mt][nt] = __builtin_amdgcn_mfma_f32_16x16x32_bf16(a[mt], b1f, acc1[mt][nt], 0, 0, 0);
      }
    }
    __builtin_amdgcn_s_setprio(0);
  };

  STAGE(0, 0);
  #pragma unroll 2
  for (int kt = 0; kt < 63; ++kt) {
    __builtin_amdgcn_s_barrier();
    __builtin_amdgcn_sched_barrier(0);
    STAGE(kt + 1, (kt + 1) & 1);
    asm volatile("s_waitcnt vmcnt(6)" ::: "memory");
    __builtin_amdgcn_s_barrier();
    __builtin_amdgcn_sched_barrier(0);
    COMPUTE(kt & 1);
  }
  asm volatile("s_waitcnt vmcnt(0)" ::: "memory");
  __builtin_amdgcn_s_barrier();
  __builtin_amdgcn_sched_barrier(0);
  COMPUTE(1);

  // epilogue: LDS transpose -> coalesced float4 row stores
  __syncthreads();
  float* smf = (float*)sm;
  float bi0[4], bi1[4];
  #pragma unroll
  for (int nt = 0; nt < 4; ++nt) {
    int c = nbase + wn + (nt << 4) + lr;
    bi0[nt] = b0[c]; bi1[nt] = b1[c];
  }
  #pragma unroll
  for (int mt = 0; mt < 4; ++mt) {
    #pragma unroll
    for (int nt = 0; nt < 4; ++nt) {
      f32x4 v0 = acc0[mt][nt], v1 = acc1[mt][nt];
      #pragma unroll
      for (int rr = 0; rr < 4; ++rr) {
        int pos = tok0 + wm + (mt << 4) + (lg << 2) + rr;
        float val = (pos >= n0) ? (v1[rr] + bi1[nt]) : (v0[rr] + bi0[nt]);
        smf[wv * 1088 + ((lg << 2) + rr) * 68 + (nt << 4) + lr] = val;
      }
    }
    #pragma unroll
    for (int p = 0; p < 4; ++p) {
      int row = (p << 2) + (ln >> 4);
      f32x4 vv = *(const f32x4*)&smf[wv * 1088 + row * 68 + ((ln & 15) << 2)];
      int tok = perm[tok0 + wm + (mt << 4) + row];
      *(f32x4*)&out[(size_t)tok * CIN + nbase + wn + ((ln & 15) << 2)] = vv;
    }
  }
}

// ---------------------------------------------------------------------------
extern "C" void kernel_launch(void* const* d_in, const int* in_sizes, int n_in,
                              void* d_out, int out_size, void* d_ws, size_t ws_size,
                              hipStream_t stream) {
  (void)in_sizes; (void)n_in; (void)out_size; (void)ws_size;
  const float* x   = (const float*)d_in[0];
  const float* wg1 = (const float*)d_in[3];
  const float* w0  = (const float*)d_in[4];
  const float* b0  = (const float*)d_in[5];
  const float* w1  = (const float*)d_in[6];
  const float* b1  = (const float*)d_in[7];
  const float* dww = (const float*)d_in[8];
  const float* dwb = (const float*)d_in[9];
  const float* wg2 = (const float*)d_in[10];
  const float* w20 = (const float*)d_in[11];
  const float* b20 = (const float*)d_in[12];
  const float* w21 = (const float*)d_in[13];
  const float* b21 = (const float*)d_in[14];
  float* out = (float*)d_out;

  char* ws = (char*)d_ws;
  const size_t MB2 = 1u << 21;
  unsigned short* w0hi = (unsigned short*)(ws + 0 * MB2);
  unsigned short* w0lo = (unsigned short*)(ws + 1 * MB2);
  unsigned short* w1q  = (unsigned short*)(ws + 2 * MB2);
  unsigned short* w20b = (unsigned short*)(ws + 3 * MB2);
  unsigned short* w21b = (unsigned short*)(ws + 4 * MB2);
  char* p = ws + 5 * MB2;
  unsigned short* xhi = (unsigned short*)p;            p += (size_t)TOKS * CIN * 2;
  unsigned short* xlo = (unsigned short*)p;            p += (size_t)TOKS * CIN * 2;
  unsigned char* pick1 = (unsigned char*)p;            p += 65536;
  unsigned char* pick2 = (unsigned char*)p;            p += 65536;
  int* perm1 = (int*)p;                                p += TOKS * 4;
  int* perm2 = (int*)p;                                p += TOKS * 4;
  int* n0a   = (int*)p;                                p += 256;
  int* n0b   = (int*)p;                                p += 256;
  float* part = (float*)p;                             p += (size_t)TOKS * 128 * 4;
  float* h32  = (float*)p;                             p += (size_t)TOKS * DHID * 4;
  unsigned short* hb = (unsigned short*)p;             // +64 MiB; total ~245 MiB

  k_prep <<<4096, 256, 0, stream>>>(w0, w1, w20, w21, w0hi, w0lo, w1q, w20b, w21b);
  k_prepx<<<8192, 256, 0, stream>>>(x, xhi, xlo);
  k_gate1<<<4096, 256, 0, stream>>>(x, wg1, pick1);
  k_scan <<<1, 1024, 0, stream>>>(pick1, perm1, n0a);
  k_fc1  <<<2048, 256, 0, stream>>>(xhi, xlo, w0hi, w0lo, w1q, b0, b1, perm1, n0a, h32);
  k_conv <<<dim3(64, 4, 16), 256, 0, stream>>>(h32, dww, dwb, wg2, hb, part);
  k_gate2<<<4096, 256, 0, stream>>>(part, pick2);
  k_scan <<<1, 1024, 0, stream>>>(pick2, perm2, n0b);
  k_fc2  <<<512, 256, 0, stream>>>(hb, w20b, w21b, b20, b21, perm2, n0b, out);
}

// Round 5
// 417.955 us; speedup vs baseline: 1.0569x; 1.0158x over previous
//
#include <hip/hip_runtime.h>
#include <hip/hip_bf16.h>

// ---------------------------------------------------------------------------
// Mlp_FMoE: fc1(MoE 2-expert top-1) -> DWConv3x3 -> GELU(exact) -> fc2(MoE)
// B=16 N=1024 C=512 Dh=2048 H=W=32, fp32 in/out.
// R5: expert-split GEMM kernels (E0 dense / E1 shift), A operands direct
//     global->VGPR (no LDS), B via 3-buffer depth-2 counted-vmcnt pipeline,
//     fc2 BK=64; fused x-split+gate1; shuffle scan.
// ---------------------------------------------------------------------------

#define TOKS  16384
#define CIN   512
#define DHID  2048

typedef __attribute__((ext_vector_type(8))) __bf16 bf16x8;
typedef __attribute__((ext_vector_type(4))) float  f32x4;
typedef __attribute__((ext_vector_type(4))) float  float4v;
typedef __attribute__((ext_vector_type(4))) unsigned short ushort4v;
typedef __attribute__((ext_vector_type(8))) unsigned short ushort8;

__device__ __forceinline__ unsigned short f2bf(float f) {
  union { float f; unsigned int u; } a; a.f = f;
  unsigned int u = a.u;
  unsigned int r = u + 0x7FFFu + ((u >> 16) & 1u);   // RNE
  return (unsigned short)(r >> 16);
}
__device__ __forceinline__ float bf2f(unsigned short h) {
  union { unsigned int u; float f; } a; a.u = ((unsigned int)h) << 16;
  return a.f;
}

// shift_quant: sign(w)*2^clip(round(log2(|w|+1e-12)),-14,0).
// round(log2(aw)) == e + (mantissa > sqrt(2)); exact via mantissa bit test.
__device__ __forceinline__ float squant(float w) {
  if (w == 0.0f) return 0.0f;
  float aw = fabsf(w) + 1e-12f;                 // fp32 add, as reference
  union { float f; unsigned u; } a; a.f = aw;
  int e = (int)((a.u >> 23) & 0xFFu) - 127;
  unsigned frac = a.u & 0x7FFFFFu;
  int shift = e + (frac >= 0x3504F4u ? 1 : 0);  // frac of sqrt(2)
  shift = min(max(shift, -14), 0);
  union { unsigned u; float f; } q; q.u = (unsigned)(shift + 127) << 23;
  return (w > 0.0f) ? q.f : -q.f;
}

#define GLDS16(gp, lp) __builtin_amdgcn_global_load_lds(                      \
    (const __attribute__((address_space(1))) void*)(gp),                      \
    (__attribute__((address_space(3))) void*)(lp), 16, 0, 0)

#define SBAR()  { __builtin_amdgcn_s_barrier(); __builtin_amdgcn_sched_barrier(0); }
#define VMCNT(n) asm volatile("s_waitcnt vmcnt(" #n ")" ::: "memory")

// ------------------------- weight prep -------------------------------------
__global__ void k_prep(const float* __restrict__ w0, const float* __restrict__ w1,
                       const float* __restrict__ w20, const float* __restrict__ w21,
                       unsigned short* __restrict__ w0hi, unsigned short* __restrict__ w0lo,
                       unsigned short* __restrict__ w1q, unsigned short* __restrict__ w20b,
                       unsigned short* __restrict__ w21b) {
  int i = blockIdx.x * 256 + threadIdx.x;
  if (i >= DHID * CIN) return;
  float v = w0[i];
  unsigned short h = f2bf(v);
  w0hi[i] = h;
  w0lo[i] = f2bf(v - bf2f(h));
  w1q[i]  = f2bf(squant(w1[i]));
  w20b[i] = f2bf(w20[i]);
  w21b[i] = f2bf(squant(w21[i]));
}

// ---------------- fused: x hi/lo split + gate1 (fp32 exact) -----------------
__global__ void k_prepg(const float* __restrict__ x, const float* __restrict__ wg1,
                        unsigned short* __restrict__ xhi, unsigned short* __restrict__ xlo,
                        unsigned char* __restrict__ pick1) {
  __shared__ float wg[1024];
  const int t = threadIdx.x;
  #pragma unroll
  for (int i = 0; i < 4; ++i) wg[t + i * 256] = wg1[t + i * 256];
  __syncthreads();
  const int tok = blockIdx.x * 4 + (t >> 6);
  const int l = t & 63;
  const float* xr = x + (size_t)tok * CIN + l * 8;
  float4v v0 = *(const float4v*)xr;
  float4v v1 = *(const float4v*)(xr + 4);
  float s0 = 0.f, s1 = 0.f;
  ushort8 hv, lv;
  #pragma unroll
  for (int j = 0; j < 8; ++j) {
    float v = (j < 4) ? v0[j] : v1[j - 4];
    unsigned short h = f2bf(v);
    hv[j] = h;
    lv[j] = f2bf(v - bf2f(h));
    int c = l * 8 + j;
    s0 += v * wg[c * 2];
    s1 += v * wg[c * 2 + 1];
  }
  *(ushort8*)&xhi[(size_t)tok * CIN + l * 8] = hv;
  *(ushort8*)&xlo[(size_t)tok * CIN + l * 8] = lv;
  for (int m = 32; m; m >>= 1) { s0 += __shfl_xor(s0, m); s1 += __shfl_xor(s1, m); }
  if (l == 0) pick1[tok] = (s0 >= s1) ? 0 : 1;   // argmax==0 on tie
}

// --------------- stable partition: perm = [expert0 toks..., expert1 toks...]
__global__ void k_scan(const unsigned char* __restrict__ pick, int* __restrict__ perm,
                       int* __restrict__ n0buf) {
  __shared__ int wpre[17];
  const int t = threadIdx.x;            // 1024
  const int lane = t & 63, w = t >> 6;  // 16 waves
  unsigned char loc[16]; int c0 = 0;
  #pragma unroll
  for (int i = 0; i < 16; ++i) { loc[i] = pick[t * 16 + i]; c0 += (loc[i] == 0); }
  int s = c0;
  #pragma unroll
  for (int off = 1; off < 64; off <<= 1) {
    int v = __shfl_up(s, off);
    if (lane >= off) s += v;
  }
  if (lane == 63) wpre[w + 1] = s;
  if (t == 0) wpre[0] = 0;
  __syncthreads();
  if (t == 0) {
    for (int j = 1; j <= 16; ++j) wpre[j] += wpre[j - 1];
    n0buf[0] = wpre[16];
  }
  __syncthreads();
  int total0 = wpre[16];
  int pre0 = wpre[w] + s - c0;
  int pre1 = t * 16 - pre0;
  int p0 = pre0, p1 = total0 + pre1;
  #pragma unroll
  for (int i = 0; i < 16; ++i) {
    int tok = t * 16 + i;
    if (loc[i] == 0) perm[p0++] = tok; else perm[p1++] = tok;
  }
}

// ------------------------- fc1 E0 (dense expert, bf16x3) --------------------
// 128x128, BK=32, 16 K-steps. A: global->reg (hi+lo). B: w0hi/w0lo via GLDS,
// 3 LDS buffers, stage 2 ahead. vmcnt FIFO: steady 16, tail 12, 0.
__launch_bounds__(256, 2)
__global__ void k_fc1_e0(const unsigned short* __restrict__ xhi,
                         const unsigned short* __restrict__ xlo,
                         const unsigned short* __restrict__ w0hi,
                         const unsigned short* __restrict__ w0lo,
                         const float* __restrict__ b0,
                         const int* __restrict__ perm, const int* __restrict__ n0buf,
                         float* __restrict__ h32) {
  __shared__ unsigned short sm[24576];   // 48 KiB: 3 bufs x {w0hi,w0lo} x 4096
  const int n0 = n0buf[0];
  const int t = threadIdx.x, wv = t >> 6, ln = t & 63;
  const int lr = ln & 15, lg = ln >> 4;
  const int g = blockIdx.x, q = g >> 3;
  const int tok0 = ((g & 7) + ((q >> 4) << 3)) * 128;
  const int nbase = (q & 15) * 128;
  if (tok0 >= n0) return;
  const int wm = (wv >> 1) * 64, wn = (wv & 1) * 64;

  int rowoff[4];
  #pragma unroll
  for (int mt = 0; mt < 4; ++mt)
    rowoff[mt] = perm[tok0 + wm + (mt << 4) + lr] * CIN + (lg << 3);

  const int swsrc = (((ln & 3) ^ ((ln >> 3) & 3)) << 3);
  const int swrd  = ((lg ^ ((lr >> 1) & 3)) << 3);

  f32x4 acc[4][4];
  #pragma unroll
  for (int i = 0; i < 4; ++i)
    #pragma unroll
    for (int j = 0; j < 4; ++j) acc[i][j] = f32x4{0.f, 0.f, 0.f, 0.f};

  auto STAGEB = [&](int kt, int db) {   // 4 GLDS per wave
    const int k0 = kt * 32;
    #pragma unroll
    for (int s = 0; s < 2; ++s) {
      const int rowblk = s * 4 + wv;
      size_t gb = (size_t)(nbase + (rowblk << 4) + (ln >> 2)) * CIN + k0 + swsrc;
      GLDS16(w0hi + gb, &sm[db * 8192 + (rowblk << 9)]);
      GLDS16(w0lo + gb, &sm[db * 8192 + 4096 + (rowblk << 9)]);
    }
  };
  auto LOADA = [&](bf16x8 (&ah)[4], bf16x8 (&al)[4], int kt) {   // 8 loads
    const int k0 = kt * 32;
    #pragma unroll
    for (int mt = 0; mt < 4; ++mt) {
      ah[mt] = *(const bf16x8*)&xhi[rowoff[mt] + k0];
      al[mt] = *(const bf16x8*)&xlo[rowoff[mt] + k0];
    }
  };
  auto COMPUTE = [&](const bf16x8 (&ah)[4], const bf16x8 (&al)[4], int db) {
    __builtin_amdgcn_s_setprio(1);
    #pragma unroll
    for (int nt = 0; nt < 4; ++nt) {
      int bb = db * 8192 + (wn + (nt << 4) + lr) * 32 + swrd;
      bf16x8 bh = *(const bf16x8*)&sm[bb];
      bf16x8 bl = *(const bf16x8*)&sm[bb + 4096];
      #pragma unroll
      for (int mt = 0; mt < 4; ++mt) {
        acc[mt][nt] = __builtin_amdgcn_mfma_f32_16x16x32_bf16(ah[mt], bh, acc[mt][nt], 0, 0, 0);
        acc[mt][nt] = __builtin_amdgcn_mfma_f32_16x16x32_bf16(al[mt], bh, acc[mt][nt], 0, 0, 0);
        acc[mt][nt] = __builtin_amdgcn_mfma_f32_16x16x32_bf16(ah[mt], bl, acc[mt][nt], 0, 0, 0);
      }
    }
    __builtin_amdgcn_s_setprio(0);
  };

  bf16x8 Ah0[4], Al0[4], Ah1[4], Al1[4];
  LOADA(Ah0, Al0, 0);
  STAGEB(0, 0);
  STAGEB(1, 1);
  for (int kt = 0; kt < 14; kt += 2) {
    SBAR();
    LOADA(Ah1, Al1, kt + 1);
    STAGEB(kt + 2, (kt + 2) % 3);
    VMCNT(16);
    SBAR();
    COMPUTE(Ah0, Al0, kt % 3);
    SBAR();
    LOADA(Ah0, Al0, kt + 2);
    STAGEB(kt + 3, (kt + 3) % 3);
    VMCNT(16);
    SBAR();
    COMPUTE(Ah1, Al1, (kt + 1) % 3);
  }
  SBAR();
  LOADA(Ah1, Al1, 15);
  VMCNT(12);
  SBAR();
  COMPUTE(Ah0, Al0, 2);          // kt=14, 14%3=2
  SBAR();
  VMCNT(0);
  SBAR();
  COMPUTE(Ah1, Al1, 0);          // kt=15, 15%3=0

  // epilogue: LDS transpose -> coalesced float4 stores, row-guarded (<n0)
  __syncthreads();
  float* smf = (float*)sm;
  float bi[4];
  #pragma unroll
  for (int nt = 0; nt < 4; ++nt) bi[nt] = b0[nbase + wn + (nt << 4) + lr];
  #pragma unroll
  for (int mt = 0; mt < 4; ++mt) {
    #pragma unroll
    for (int nt = 0; nt < 4; ++nt) {
      f32x4 v = acc[mt][nt];
      #pragma unroll
      for (int rr = 0; rr < 4; ++rr)
        smf[wv * 1088 + ((lg << 2) + rr) * 68 + (nt << 4) + lr] = v[rr] + bi[nt];
    }
    #pragma unroll
    for (int p = 0; p < 4; ++p) {
      int row = (p << 2) + (ln >> 4);
      int pos = tok0 + wm + (mt << 4) + row;
      if (pos < n0) {
        f32x4 vv = *(const f32x4*)&smf[wv * 1088 + row * 68 + ((ln & 15) << 2)];
        *(f32x4*)&h32[(size_t)perm[pos] * DHID + nbase + wn + ((ln & 15) << 2)] = vv;
      }
    }
  }
}

// ------------------------- fc1 E1 (shift expert, bf16x2) --------------------
__launch_bounds__(256, 2)
__global__ void k_fc1_e1(const unsigned short* __restrict__ xhi,
                         const unsigned short* __restrict__ xlo,
                         const unsigned short* __restrict__ w1q,
                         const float* __restrict__ b1,
                         const int* __restrict__ perm, const int* __restrict__ n0buf,
                         float* __restrict__ h32) {
  __shared__ unsigned short sm[12288];   // 24 KiB: 3 bufs x 4096
  const int n0 = n0buf[0];
  const int t = threadIdx.x, wv = t >> 6, ln = t & 63;
  const int lr = ln & 15, lg = ln >> 4;
  const int g = blockIdx.x, q = g >> 3;
  const int tok0 = ((g & 7) + ((q >> 4) << 3)) * 128;
  const int nbase = (q & 15) * 128;
  if (tok0 + 128 <= n0) return;
  const int wm = (wv >> 1) * 64, wn = (wv & 1) * 64;

  int rowoff[4];
  #pragma unroll
  for (int mt = 0; mt < 4; ++mt)
    rowoff[mt] = perm[tok0 + wm + (mt << 4) + lr] * CIN + (lg << 3);

  const int swsrc = (((ln & 3) ^ ((ln >> 3) & 3)) << 3);
  const int swrd  = ((lg ^ ((lr >> 1) & 3)) << 3);

  f32x4 acc[4][4];
  #pragma unroll
  for (int i = 0; i < 4; ++i)
    #pragma unroll
    for (int j = 0; j < 4; ++j) acc[i][j] = f32x4{0.f, 0.f, 0.f, 0.f};

  auto STAGEB = [&](int kt, int db) {   // 2 GLDS per wave
    const int k0 = kt * 32;
    #pragma unroll
    for (int s = 0; s < 2; ++s) {
      const int rowblk = s * 4 + wv;
      size_t gb = (size_t)(nbase + (rowblk << 4) + (ln >> 2)) * CIN + k0 + swsrc;
      GLDS16(w1q + gb, &sm[db * 4096 + (rowblk << 9)]);
    }
  };
  auto LOADA = [&](bf16x8 (&ah)[4], bf16x8 (&al)[4], int kt) {
    const int k0 = kt * 32;
    #pragma unroll
    for (int mt = 0; mt < 4; ++mt) {
      ah[mt] = *(const bf16x8*)&xhi[rowoff[mt] + k0];
      al[mt] = *(const bf16x8*)&xlo[rowoff[mt] + k0];
    }
  };
  auto COMPUTE = [&](const bf16x8 (&ah)[4], const bf16x8 (&al)[4], int db) {
    __builtin_amdgcn_s_setprio(1);
    #pragma unroll
    for (int nt = 0; nt < 4; ++nt) {
      bf16x8 bq = *(const bf16x8*)&sm[db * 4096 + (wn + (nt << 4) + lr) * 32 + swrd];
      #pragma unroll
      for (int mt = 0; mt < 4; ++mt) {
        acc[mt][nt] = __builtin_amdgcn_mfma_f32_16x16x32_bf16(ah[mt], bq, acc[mt][nt], 0, 0, 0);
        acc[mt][nt] = __builtin_amdgcn_mfma_f32_16x16x32_bf16(al[mt], bq, acc[mt][nt], 0, 0, 0);
      }
    }
    __builtin_amdgcn_s_setprio(0);
  };

  bf16x8 Ah0[4], Al0[4], Ah1[4], Al1[4];
  LOADA(Ah0, Al0, 0);
  STAGEB(0, 0);
  STAGEB(1, 1);
  for (int kt = 0; kt < 14; kt += 2) {
    SBAR();
    LOADA(Ah1, Al1, kt + 1);
    STAGEB(kt + 2, (kt + 2) % 3);
    VMCNT(12);
    SBAR();
    COMPUTE(Ah0, Al0, kt % 3);
    SBAR();
    LOADA(Ah0, Al0, kt + 2);
    STAGEB(kt + 3, (kt + 3) % 3);
    VMCNT(12);
    SBAR();
    COMPUTE(Ah1, Al1, (kt + 1) % 3);
  }
  SBAR();
  LOADA(Ah1, Al1, 15);
  VMCNT(10);
  SBAR();
  COMPUTE(Ah0, Al0, 2);
  SBAR();
  VMCNT(0);
  SBAR();
  COMPUTE(Ah1, Al1, 0);

  __syncthreads();
  float* smf = (float*)sm;
  float bi[4];
  #pragma unroll
  for (int nt = 0; nt < 4; ++nt) bi[nt] = b1[nbase + wn + (nt << 4) + lr];
  #pragma unroll
  for (int mt = 0; mt < 4; ++mt) {
    #pragma unroll
    for (int nt = 0; nt < 4; ++nt) {
      f32x4 v = acc[mt][nt];
      #pragma unroll
      for (int rr = 0; rr < 4; ++rr)
        smf[wv * 1088 + ((lg << 2) + rr) * 68 + (nt << 4) + lr] = v[rr] + bi[nt];
    }
    #pragma unroll
    for (int p = 0; p < 4; ++p) {
      int row = (p << 2) + (ln >> 4);
      int pos = tok0 + wm + (mt << 4) + row;
      if (pos >= n0) {
        f32x4 vv = *(const f32x4*)&smf[wv * 1088 + row * 68 + ((ln & 15) << 2)];
        *(f32x4*)&h32[(size_t)perm[pos] * DHID + nbase + wn + ((ln & 15) << 2)] = vv;
      }
    }
  }
}

// ---------------- DWConv3x3 + bias + exact GELU + gate2 partials ------------
__launch_bounds__(256)
__global__ void k_conv(const float* __restrict__ h32, const float* __restrict__ dww,
                       const float* __restrict__ dwb, const float* __restrict__ wg2,
                       unsigned short* __restrict__ hb, float* __restrict__ part) {
  __shared__ float4v tile[10][32][8];   // 40 KiB
  const int dc = blockIdx.x;   // 0..63
  const int ys = blockIdx.y;   // 0..3
  const int b  = blockIdx.z;   // 0..15
  const int t = threadIdx.x;
  const int d0 = dc * 32, y0 = ys * 8;
  const int dl4 = t & 7, xq = t >> 3;

  #pragma unroll
  for (int ry = 0; ry < 10; ++ry) {
    int y = y0 - 1 + ry;
    float4v v = {0.f, 0.f, 0.f, 0.f};
    if (y >= 0 && y < 32)
      v = *(const float4v*)&h32[(size_t)(b * 1024 + y * 32 + xq) * DHID + d0 + dl4 * 4];
    tile[ry][xq][dl4] = v;
  }
  __syncthreads();

  const int d = d0 + dl4 * 4;
  float4v kk[9];
  #pragma unroll
  for (int i = 0; i < 9; ++i) {
    kk[i][0] = dww[(d + 0) * 9 + i]; kk[i][1] = dww[(d + 1) * 9 + i];
    kk[i][2] = dww[(d + 2) * 9 + i]; kk[i][3] = dww[(d + 3) * 9 + i];
  }
  const float4v bias = *(const float4v*)&dwb[d];
  float4v g0v, g1v;
  #pragma unroll
  for (int j = 0; j < 4; ++j) { g0v[j] = wg2[(d + j) * 2]; g1v[j] = wg2[(d + j) * 2 + 1]; }

  #pragma unroll
  for (int yy = 0; yy < 8; ++yy) {
    float4v s = bias;
    #pragma unroll
    for (int dy = 0; dy < 3; ++dy)
      #pragma unroll
      for (int dx = 0; dx < 3; ++dx) {
        int xs = xq + dx - 1;
        if (xs >= 0 && xs < 32) {
          float4v v = tile[yy + dy][xs][dl4];
          float4v k = kk[dy * 3 + dx];
          s[0] += v[0] * k[0]; s[1] += v[1] * k[1];
          s[2] += v[2] * k[2]; s[3] += v[3] * k[3];
        }
      }
    float4v gg;
    #pragma unroll
    for (int j = 0; j < 4; ++j)
      gg[j] = 0.5f * s[j] * (1.0f + erff(s[j] * 0.70710678118654752f));  // exact
    int tok = b * 1024 + (y0 + yy) * 32 + xq;
    ushort4v hv;
    #pragma unroll
    for (int j = 0; j < 4; ++j) hv[j] = f2bf(gg[j]);
    *(ushort4v*)&hb[(size_t)tok * DHID + d] = hv;
    float p0 = gg[0] * g0v[0] + gg[1] * g0v[1] + gg[2] * g0v[2] + gg[3] * g0v[3];
    float p1 = gg[0] * g1v[0] + gg[1] * g1v[1] + gg[2] * g1v[2] + gg[3] * g1v[3];
    p0 += __shfl_xor(p0, 1); p0 += __shfl_xor(p0, 2); p0 += __shfl_xor(p0, 4);
    p1 += __shfl_xor(p1, 1); p1 += __shfl_xor(p1, 2); p1 += __shfl_xor(p1, 4);
    if (dl4 == 0) {
      part[(size_t)tok * 128 + dc] = p0;
      part[(size_t)tok * 128 + 64 + dc] = p1;
    }
  }
}

// ------------------------- gate 2 reduce (wave per token) -------------------
__global__ void k_gate2(const float* __restrict__ part, unsigned char* __restrict__ pick2) {
  int tok = blockIdx.x * 4 + (threadIdx.x >> 6);
  int l = threadIdx.x & 63;
  const float* pr = part + (size_t)tok * 128;
  float s0 = pr[l], s1 = pr[64 + l];
  for (int m = 32; m; m >>= 1) { s0 += __shfl_xor(s0, m); s1 += __shfl_xor(s1, m); }
  if (l == 0) pick2[tok] = (s0 >= s1) ? 0 : 1;
}

// ------------------------- fc2 E0/E1: BK=64, A reg, B pipelined -------------
// 128x128, 32 K-steps of 64. LDS: 3 bufs x (2 ksub x 4096) = 48 KiB.
template <int EXPERT>
__launch_bounds__(256, 2)
__global__ void k_fc2_e(const unsigned short* __restrict__ hb,
                        const unsigned short* __restrict__ wb,
                        const float* __restrict__ bias_v,
                        const int* __restrict__ perm, const int* __restrict__ n0buf,
                        float* __restrict__ out) {
  __shared__ unsigned short sm[24576];   // 48 KiB
  const int n0 = n0buf[0];
  const int t = threadIdx.x, wv = t >> 6, ln = t & 63;
  const int lr = ln & 15, lg = ln >> 4;
  const int g = blockIdx.x, q = g >> 3;
  const int tok0 = ((g & 7) + ((q >> 2) << 3)) * 128;
  const int nbase = (q & 3) * 128;
  if (EXPERT == 0) { if (tok0 >= n0) return; }
  else             { if (tok0 + 128 <= n0) return; }
  const int wm = (wv >> 1) * 64, wn = (wv & 1) * 64;

  int rowoff[4];
  #pragma unroll
  for (int mt = 0; mt < 4; ++mt)
    rowoff[mt] = perm[tok0 + wm + (mt << 4) + lr] * DHID + (lg << 3);

  const int swsrc = (((ln & 3) ^ ((ln >> 3) & 3)) << 3);
  const int swrd  = ((lg ^ ((lr >> 1) & 3)) << 3);

  f32x4 acc[4][4];
  #pragma unroll
  for (int i = 0; i < 4; ++i)
    #pragma unroll
    for (int j = 0; j < 4; ++j) acc[i][j] = f32x4{0.f, 0.f, 0.f, 0.f};

  auto STAGEB = [&](int kt, int db) {   // 4 GLDS per wave (2 ksubs)
    #pragma unroll
    for (int ks = 0; ks < 2; ++ks) {
      const int k0 = kt * 64 + ks * 32;
      #pragma unroll
      for (int s = 0; s < 2; ++s) {
        const int rowblk = s * 4 + wv;
        size_t gb = (size_t)(nbase + (rowblk << 4) + (ln >> 2)) * DHID + k0 + swsrc;
        GLDS16(wb + gb, &sm[db * 8192 + ks * 4096 + (rowblk << 9)]);
      }
    }
  };
  auto LOADA = [&](bf16x8 (&a)[8], int kt) {   // 8 loads
    #pragma unroll
    for (int ks = 0; ks < 2; ++ks) {
      const int k0 = kt * 64 + ks * 32;
      #pragma unroll
      for (int mt = 0; mt < 4; ++mt)
        a[ks * 4 + mt] = *(const bf16x8*)&hb[rowoff[mt] + k0];
    }
  };
  auto COMPUTE = [&](const bf16x8 (&a)[8], int db) {
    __builtin_amdgcn_s_setprio(1);
    #pragma unroll
    for (int ks = 0; ks < 2; ++ks) {
      #pragma unroll
      for (int nt = 0; nt < 4; ++nt) {
        bf16x8 bf = *(const bf16x8*)&sm[db * 8192 + ks * 4096 + (wn + (nt << 4) + lr) * 32 + swrd];
        #pragma unroll
        for (int mt = 0; mt < 4; ++mt)
          acc[mt][nt] = __builtin_amdgcn_mfma_f32_16x16x32_bf16(a[ks * 4 + mt], bf, acc[mt][nt], 0, 0, 0);
      }
    }
    __builtin_amdgcn_s_setprio(0);
  };

  bf16x8 A0[8], A1[8];
  LOADA(A0, 0);
  STAGEB(0, 0);
  STAGEB(1, 1);
  for (int kt = 0; kt < 30; kt += 2) {
    SBAR();
    LOADA(A1, kt + 1);
    STAGEB(kt + 2, (kt + 2) % 3);
    VMCNT(16);
    SBAR();
    COMPUTE(A0, kt % 3);
    SBAR();
    LOADA(A0, kt + 2);
    STAGEB(kt + 3, (kt + 3) % 3);
    VMCNT(16);
    SBAR();
    COMPUTE(A1, (kt + 1) % 3);
  }
  SBAR();
  LOADA(A1, 31);
  VMCNT(12);
  SBAR();
  COMPUTE(A0, 0);               // kt=30, 30%3=0
  SBAR();
  VMCNT(0);
  SBAR();
  COMPUTE(A1, 1);               // kt=31, 31%3=1

  __syncthreads();
  float* smf = (float*)sm;
  float bi[4];
  #pragma unroll
  for (int nt = 0; nt < 4; ++nt) bi[nt] = bias_v[nbase + wn + (nt << 4) + lr];
  #pragma unroll
  for (int mt = 0; mt < 4; ++mt) {
    #pragma unroll
    for (int nt = 0; nt < 4; ++nt) {
      f32x4 v = acc[mt][nt];
      #pragma unroll
      for (int rr = 0; rr < 4; ++rr)
        smf[wv * 1088 + ((lg << 2) + rr) * 68 + (nt << 4) + lr] = v[rr] + bi[nt];
    }
    #pragma unroll
    for (int p = 0; p < 4; ++p) {
      int row = (p << 2) + (ln >> 4);
      int pos = tok0 + wm + (mt << 4) + row;
      bool store = (EXPERT == 0) ? (pos < n0) : (pos >= n0);
      if (store) {
        f32x4 vv = *(const f32x4*)&smf[wv * 1088 + row * 68 + ((ln & 15) << 2)];
        *(f32x4*)&out[(size_t)perm[pos] * CIN + nbase + wn + ((ln & 15) << 2)] = vv;
      }
    }
  }
}

// ---------------------------------------------------------------------------
extern "C" void kernel_launch(void* const* d_in, const int* in_sizes, int n_in,
                              void* d_out, int out_size, void* d_ws, size_t ws_size,
                              hipStream_t stream) {
  (void)in_sizes; (void)n_in; (void)out_size; (void)ws_size;
  const float* x   = (const float*)d_in[0];
  const float* wg1 = (const float*)d_in[3];
  const float* w0  = (const float*)d_in[4];
  const float* b0  = (const float*)d_in[5];
  const float* w1  = (const float*)d_in[6];
  const float* b1  = (const float*)d_in[7];
  const float* dww = (const float*)d_in[8];
  const float* dwb = (const float*)d_in[9];
  const float* wg2 = (const float*)d_in[10];
  const float* w20 = (const float*)d_in[11];
  const float* b20 = (const float*)d_in[12];
  const float* w21 = (const float*)d_in[13];
  const float* b21 = (const float*)d_in[14];
  float* out = (float*)d_out;

  char* ws = (char*)d_ws;
  const size_t MB2 = 1u << 21;
  unsigned short* w0hi = (unsigned short*)(ws + 0 * MB2);
  unsigned short* w0lo = (unsigned short*)(ws + 1 * MB2);
  unsigned short* w1q  = (unsigned short*)(ws + 2 * MB2);
  unsigned short* w20b = (unsigned short*)(ws + 3 * MB2);
  unsigned short* w21b = (unsigned short*)(ws + 4 * MB2);
  char* p = ws + 5 * MB2;
  unsigned short* xhi = (unsigned short*)p;            p += (size_t)TOKS * CIN * 2;
  unsigned short* xlo = (unsigned short*)p;            p += (size_t)TOKS * CIN * 2;
  unsigned char* pick1 = (unsigned char*)p;            p += 65536;
  unsigned char* pick2 = (unsigned char*)p;            p += 65536;
  int* perm1 = (int*)p;                                p += TOKS * 4;
  int* perm2 = (int*)p;                                p += TOKS * 4;
  int* n0a   = (int*)p;                                p += 256;
  int* n0b   = (int*)p;                                p += 256;
  float* part = (float*)p;                             p += (size_t)TOKS * 128 * 4;
  float* h32  = (float*)p;                             p += (size_t)TOKS * DHID * 4;
  unsigned short* hb = (unsigned short*)p;             // +64 MiB; total ~245 MiB

  k_prep <<<4096, 256, 0, stream>>>(w0, w1, w20, w21, w0hi, w0lo, w1q, w20b, w21b);
  k_prepg<<<4096, 256, 0, stream>>>(x, wg1, xhi, xlo, pick1);
  k_scan <<<1, 1024, 0, stream>>>(pick1, perm1, n0a);
  k_fc1_e0<<<2048, 256, 0, stream>>>(xhi, xlo, w0hi, w0lo, b0, perm1, n0a, h32);
  k_fc1_e1<<<2048, 256, 0, stream>>>(xhi, xlo, w1q, b1, perm1, n0a, h32);
  k_conv <<<dim3(64, 4, 16), 256, 0, stream>>>(h32, dww, dwb, wg2, hb, part);
  k_gate2<<<4096, 256, 0, stream>>>(part, pick2);
  k_scan <<<1, 1024, 0, stream>>>(pick2, perm2, n0b);
  k_fc2_e<0><<<512, 256, 0, stream>>>(hb, w20b, b20, perm2, n0b, out);
  k_fc2_e<1><<<512, 256, 0, stream>>>(hb, w21b, b21, perm2, n0b, out);
}